// Round 10
// baseline (111.395 us; speedup 1.0000x reference)
//
#include <hip/hip_runtime.h>
#include <math.h>

#define NSAMP 32768
#define FS_F 44100.0f
#define PI_F 3.14159265358979323846f
#define T1 1024  // KS slice length (32 slices/batch)
#define FLAG_MAGIC 0x5A5A5A5A

// LDS layout (floats, dynamic):
//   xall [0, 33792)      whole-span preLP'd excitation (32768 + 1024 pad)
//   prog [33792,33808)   per-segment ready flags (16 ints)
//   tabs [33808, 40720)  body tables (bandc/Qlev/Qw/Rtab)
// body overlays: sl = [0,5376), body lws/lc0/lc1 at [6144..6248)
#define XALL_FLOATS 33792
#define PROG_OFF 33792
#define TABS_OFF 33808
#define SMEM_FLOATS 40720  // 162880 bytes (<= 163840)

struct BParams {
  float alpha, alpha_p;
  float fr, g, s;
  int Di;
  float lc, lm, lp;
};

__device__ inline float sigmoidf_(float x) { return 1.0f / (1.0f + expf(-x)); }

__device__ inline BParams compute_params(int b, const float* __restrict__ pitch,
                                         const float* __restrict__ w1,
                                         const float* __restrict__ b1,
                                         const float* __restrict__ w2,
                                         const float* __restrict__ b2) {
  BParams P;
  float p = pitch[b];
  float h[16];
#pragma unroll
  for (int i = 0; i < 16; ++i) {
    float v = fmaf(p, w1[i], b1[i]);
    h[i] = v > 0.0f ? v : 0.0f;
  }
  float m[3];
#pragma unroll
  for (int j = 0; j < 3; ++j) {
    float acc = b2[j];
#pragma unroll
    for (int i = 0; i < 16; ++i) acc = fmaf(h[i], w2[j * 16 + i], acc);
    m[j] = acc;
  }
  P.lc = fminf(fmaxf(m[0], -2.0f), 2.5f);
  P.lm = fminf(fmaxf(m[1], -2.5f), 0.0f);
  P.lp = fminf(fmaxf(m[2], -4.0f), 4.0f);
  P.g = 0.999f * sigmoidf_(P.lc);
  P.s = sigmoidf_(P.lm);
  float f0 = fmaxf(p, 60.0f);
  float D = fminf(fmaxf(FS_F / f0, 2.0f), 735.0f);
  int Di = (int)floorf(D);
  P.fr = D - (float)Di;
  P.Di = Di;
  float mult = fminf(fmaxf(2.0f + 6.0f * (f0 - 60.0f) / 600.0f, 2.0f), 8.0f);
  float cutoff = fminf(2.0f * PI_F * f0 * mult / FS_F, PI_F * 0.9f);
  P.alpha = 1.0f - expf(-cutoff);
  float cpost = fminf(PI_F * sigmoidf_(P.lp), PI_F * 0.99f);
  P.alpha_p = 1.0f - expf(-cpost);
  return P;
}

// lane helpers (wave64)
__device__ inline float rlv(float v, int l) {
  return __int_as_float(__builtin_amdgcn_readlane(__float_as_int(v), l));
}
__device__ inline float shr1(float v, float bnd) {
  return __int_as_float(__builtin_amdgcn_update_dpp(
      __float_as_int(bnd), __float_as_int(v), 0x138 /*wave_shr:1*/, 0xf, 0xf,
      false));
}
// rotate right by 1: lane0 <- lane63
__device__ inline float ror1(float v) {
  return __int_as_float(__builtin_amdgcn_update_dpp(
      __float_as_int(v), __float_as_int(v), 0x13C /*wave_ror:1*/, 0xf, 0xf,
      false));
}

__device__ inline void band_coef(int k, float& a1, float& a2, float& b0) {
  float fc = 80.0f * exp2f((float)k * (6.64385618977472436f / 23.0f));
  float w = 2.0f * PI_F * fc / FS_F;
  float r = expf(-PI_F * fc / (10.0f * FS_F));
  a1 = -2.0f * r * cosf(w);
  a2 = r * r;
  b0 = 1.0f - r;
}

// ---- data-independent body tables (verified bit-exact vs in-body compute) --
__device__ inline void gen_tables(float* __restrict__ tabs, int W) {
  if (W >= 120) return;
  const int j = W / 5, sub = W % 5;
  float A1, A2, B0;
  band_coef(j, A1, A2, B0);
  if (sub == 0) *(float4*)&tabs[j * 4] = make_float4(A1, A2, B0, 0.f);
  float Q00 = -A1, Q01 = -A2, Q10 = 1.f, Q11 = 0.f;
#pragma unroll
  for (int sq = 0; sq < 2; ++sq) {
    float n00 = fmaf(Q00, Q00, Q01 * Q10);
    float n01 = fmaf(Q00, Q01, Q01 * Q11);
    float n10 = fmaf(Q10, Q00, Q11 * Q10);
    float n11 = fmaf(Q10, Q01, Q11 * Q11);
    Q00 = n00; Q01 = n01; Q10 = n10; Q11 = n11;
  }
  float K00 = Q00, K01 = Q01, K10 = Q10, K11 = Q11;
#pragma unroll
  for (int sq = 0; sq < 2; ++sq) {
    float n00 = fmaf(Q00, Q00, Q01 * Q10);
    float n01 = fmaf(Q00, Q01, Q01 * Q11);
    float n10 = fmaf(Q10, Q00, Q11 * Q10);
    float n11 = fmaf(Q10, Q01, Q11 * Q11);
    Q00 = n00; Q01 = n01; Q10 = n10; Q11 = n11;
  }
  float L00[7], L01[7], L10[7], L11[7];
  L00[0] = fmaf(Q00, K00, Q01 * K10);
  L01[0] = fmaf(Q00, K01, Q01 * K11);
  L10[0] = fmaf(Q10, K00, Q11 * K10);
  L11[0] = fmaf(Q10, K01, Q11 * K11);
#pragma unroll
  for (int k = 0; k < 6; ++k) {
    float s00 = fmaf(L00[k], L00[k], L01[k] * L10[k]);
    float s01 = fmaf(L00[k], L01[k], L01[k] * L11[k]);
    float s10 = fmaf(L10[k], L00[k], L11[k] * L10[k]);
    float s11 = fmaf(L10[k], L01[k], L11[k] * L11[k]);
    L00[k + 1] = s00; L01[k + 1] = s01; L10[k + 1] = s10; L11[k + 1] = s11;
  }
  if (sub == 0) {
#pragma unroll
    for (int k = 0; k < 6; ++k)
      *(float4*)&tabs[96 + (k * 24 + j) * 4] =
          make_float4(L00[k], L01[k], L10[k], L11[k]);
    *(float4*)&tabs[672 + j * 4] = make_float4(L00[6], L01[6], L10[6], L11[6]);
  }
  int l0 = sub * 13, l1 = l0 + 13;
  if (l1 > 64) l1 = 64;
  for (int l = l0; l < l1; ++l) {
    float R00 = 1.f, R01 = 0.f, R10 = 0.f, R11 = 1.f;
#pragma unroll
    for (int bit = 0; bit < 6; ++bit) {
      if ((l >> bit) & 1) {
        float n00 = fmaf(L00[bit], R00, L01[bit] * R10);
        float n01 = fmaf(L00[bit], R01, L01[bit] * R11);
        float n10 = fmaf(L10[bit], R00, L11[bit] * R10);
        float n11 = fmaf(L10[bit], R01, L11[bit] * R11);
        R00 = n00; R01 = n01; R10 = n10; R11 = n11;
      }
    }
    *(float4*)&tabs[768 + (j * 64 + l) * 4] = make_float4(R00, R01, R10, R11);
  }
}

// producer: register load of one segment (32 samples/lane), guarded
__device__ inline void w1_load(const float* __restrict__ xg, int s1, int seg,
                               int lane, float4* pf) {
  const int base = s1 + (seg << 11) + (lane << 5);
#pragma unroll
  for (int i = 0; i < 8; ++i) {
    const int g = base + 4 * i;
    float4 v = make_float4(0.f, 0.f, 0.f, 0.f);
    if (g >= 0 && g + 3 < NSAMP) v = *(const float4*)&xg[g];
    pf[i] = v;
  }
}

// One KS period step. FP op sequence identical to R2..R9 (bit-identical).
#define KS_STEP(STORES)                                                       \
  do {                                                                        \
    float b2v[KNUM], b3v[KNUM];                                               \
    b2v[0] = shr1(yp[0], p1);                                                 \
    _Pragma("unroll") for (int k = 1; k < KNUM; ++k)                          \
        b2v[k] = shr1(yp[k], ror1(yp[k - 1]));                                \
    b3v[0] = shr1(b2v[0], p2);                                                \
    _Pragma("unroll") for (int k = 1; k < KNUM; ++k)                          \
        b3v[k] = shr1(b2v[k], ror1(b2v[k - 1]));                              \
    float p1n = rlv(yp[KNUM - 1], lq1);                                       \
    float p2n = rlv(b2v[KNUM - 1], lq1);                                      \
    _Pragma("unroll") for (int k = 0; k < KNUM; ++k)                          \
        yp[k] =                                                               \
            fmaf(c0w, yp[k], fmaf(c2w, b3v[k], fmaf(c1w, b2v[k], xC[k])));    \
    p1 = p1n;                                                                 \
    p2 = p2n;                                                                 \
    if (STORES) {                                                             \
      _Pragma("unroll") for (int k = 0; k < KNUM; ++k) {                      \
        int i = lane + (k << 6);                                              \
        int n = s1 + rel + i;                                                 \
        bool okl = (k < KNUM - 1) || (lane <= lq1);                           \
        if (okl && n >= n0 && n < end) yg[n] = yp[k];                         \
      }                                                                       \
    }                                                                         \
    int r2 = rel + 2 * C;                                                     \
    if (r2 < span) {                                                          \
      const float* xp = &xall[r2 + lane];                                     \
      _Pragma("unroll") for (int k = 0; k < KNUM; ++k) {                      \
        xC[k] = xN[k];                                                        \
        xN[k] = xp[k << 6];                                                   \
      }                                                                       \
    } else {                                                                  \
      _Pragma("unroll") for (int k = 0; k < KNUM; ++k) xC[k] = xN[k];         \
    }                                                                         \
    rel += C;                                                                 \
  } while (0)

// ---- single-wave KS recurrence (wave 0): flat LDS input; polls per-segment
// ready flags (producers run out-of-order mod 3, so each flag is checked).
template <int KNUM>
__device__ void ks_wave0(float* __restrict__ yg, const float* xall,
                         int* __restrict__ prog, int lane, int C, float c0w,
                         float c1w, float c2w, int s1, int n0, int end,
                         int span, int NSG) {
  const int lq1 = (C - 1) - (KNUM - 1) * 64;
  const int W = n0 - s1;
  float yp[KNUM], xC[KNUM], xN[KNUM];
  float p1 = 0.f, p2 = 0.f;
  int rel = 0;
  int done = 0;
#pragma unroll
  for (int k = 0; k < KNUM; ++k) { yp[k] = 0.f; xC[k] = 0.f; xN[k] = 0.f; }
  for (int s = 0; s < NSG; ++s) {
    int need = s + 3;
    if (need > NSG) need = NSG;
    for (; done < need; ++done) {
      while (__hip_atomic_load(&prog[done], __ATOMIC_ACQUIRE,
                               __HIP_MEMORY_SCOPE_WORKGROUP) == 0) {
        __builtin_amdgcn_s_sleep(1);
      }
    }
    if (s == 0) {
#pragma unroll
      for (int k = 0; k < KNUM; ++k) {
        int i = lane + (k << 6);
        xC[k] = xall[i];
        xN[k] = xall[C + i];
      }
    }
    int fence = (s + 1) << 11;
    if (fence > span) fence = span;
    while (rel + C <= W && rel < fence) KS_STEP(false);
    while (rel < fence) KS_STEP(true);
  }
}

// ---- KS phase: waves 1-3 produce segments ls = (wid-1), (wid-1)+3, ...
// Each producer derives its carry from the PREVIOUS segment's total computed
// from scratch (exact: c^2048 <= e^-35 makes the recursive carry term
// sub-ulp, so vrun(s) == tot(s-1) in fp32). Per-segment LDS ready flags;
// consumer (wave0) polls. Tables generated by waves 1-2 after their segments.
__device__ inline void ks_phase(int b, int q, const BParams& P,
                                const float* __restrict__ exc, float scale0,
                                float* __restrict__ buf1, float* xall,
                                int* prog, float* tabs, int t) {
  const int C = P.Di;
  const int n0 = q << 10;
  float lg = -logf(P.g);
  int Wp = (int)ceilf(10.5f / fmaxf(lg, 1e-6f));
  if (Wp > 64) Wp = 64;
  if (Wp < 4) Wp = 4;
  int W = Wp * C;
  if (W > n0) W = n0;
  W = (W + 3) & ~3;
  const int s1 = n0 - W;
  const int span = W + T1;
  const int end = n0 + T1;
  const int NSG = (span + 2047) >> 11;  // segments covering span, <= 16
  float* yg = buf1 + (size_t)b * NSAMP;
  const float* xg = exc + (size_t)b * NSAMP;

  const float c = 1.0f - P.alpha;
  const float scale = scale0 * P.alpha;
  const int lane = t & 63, wid = t >> 6;

  // init: per-segment flags + zero the pad region [NSG*2048, +1024)
  if (t < 16) prog[t] = 0;
  *(float4*)&xall[(NSG << 11) + 4 * t] = make_float4(0.f, 0.f, 0.f, 0.f);
  __syncthreads();

  const float c0w = P.g * (1.0f - P.s) * (1.0f - P.fr);
  const float c1w = P.g * ((1.0f - P.s) * P.fr + P.s * (1.0f - P.fr));
  const float c2w = P.g * P.s * P.fr;

  if (wid == 0) {
    switch ((C + 63) >> 6) {
      case 2:  ks_wave0<2>(yg, xall, prog, lane, C, c0w, c1w, c2w, s1, n0, end, span, NSG); break;
      case 3:  ks_wave0<3>(yg, xall, prog, lane, C, c0w, c1w, c2w, s1, n0, end, span, NSG); break;
      case 4:  ks_wave0<4>(yg, xall, prog, lane, C, c0w, c1w, c2w, s1, n0, end, span, NSG); break;
      case 5:  ks_wave0<5>(yg, xall, prog, lane, C, c0w, c1w, c2w, s1, n0, end, span, NSG); break;
      case 6:  ks_wave0<6>(yg, xall, prog, lane, C, c0w, c1w, c2w, s1, n0, end, span, NSG); break;
      case 7:  ks_wave0<7>(yg, xall, prog, lane, C, c0w, c1w, c2w, s1, n0, end, span, NSG); break;
      case 8:  ks_wave0<8>(yg, xall, prog, lane, C, c0w, c1w, c2w, s1, n0, end, span, NSG); break;
      case 9:  ks_wave0<9>(yg, xall, prog, lane, C, c0w, c1w, c2w, s1, n0, end, span, NSG); break;
      case 10: ks_wave0<10>(yg, xall, prog, lane, C, c0w, c1w, c2w, s1, n0, end, span, NSG); break;
      case 11: ks_wave0<11>(yg, xall, prog, lane, C, c0w, c1w, c2w, s1, n0, end, span, NSG); break;
      default: ks_wave0<12>(yg, xall, prog, lane, C, c0w, c1w, c2w, s1, n0, end, span, NSG); break;
    }
  } else {
    // ---- producers (waves 1..3) ----
    float c2v = c * c, c4 = c2v * c2v, c8 = c4 * c4;
    float m1 = c8, m2 = m1 * m1, m4 = m2 * m2, m8 = m4 * m4, m16 = m8 * m8,
          m32 = m16 * m16;
    float c512 = m32 * m32;
    const float n1 = m4, n2 = m8, n4 = m16, n8 = m32, n16 = c512,
                n32 = c512 * c512;
    const float c32lane = exp2f((float)(lane << 5) * log2f(c));
    for (int ls = wid - 1; ls < NSG; ls += 3) {
      // issue both segments' loads up front (latency overlap)
      float4 pp[8], pf[8];
      w1_load(xg, s1, ls - 1, lane, pp);  // previous segment (for carry)
      w1_load(xg, s1, ls, lane, pf);      // own segment
      // total of previous segment (same expression order as old vrun path)
      float Sp = 0.0f;
#pragma unroll
      for (int i = 0; i < 8; ++i) {
        Sp = fmaf(c, Sp, scale * pp[i].x);
        Sp = fmaf(c, Sp, scale * pp[i].y);
        Sp = fmaf(c, Sp, scale * pp[i].z);
        Sp = fmaf(c, Sp, scale * pp[i].w);
      }
      float Swp = Sp, up;
      up = __shfl_up(Swp, 1);  if (lane >= 1)  Swp = fmaf(n1, up, Swp);
      up = __shfl_up(Swp, 2);  if (lane >= 2)  Swp = fmaf(n2, up, Swp);
      up = __shfl_up(Swp, 4);  if (lane >= 4)  Swp = fmaf(n4, up, Swp);
      up = __shfl_up(Swp, 8);  if (lane >= 8)  Swp = fmaf(n8, up, Swp);
      up = __shfl_up(Swp, 16); if (lane >= 16) Swp = fmaf(n16, up, Swp);
      up = __shfl_up(Swp, 32); if (lane >= 32) Swp = fmaf(n32, up, Swp);
      float tpre = rlv(Swp, 63);  // == vrun entering segment ls (sub-ulp)
      // own segment scan
      float S = 0.0f;
#pragma unroll
      for (int i = 0; i < 8; ++i) {
        S = fmaf(c, S, scale * pf[i].x);
        S = fmaf(c, S, scale * pf[i].y);
        S = fmaf(c, S, scale * pf[i].z);
        S = fmaf(c, S, scale * pf[i].w);
      }
      float Sw = S, u;
      u = __shfl_up(Sw, 1);  if (lane >= 1)  Sw = fmaf(n1, u, Sw);
      u = __shfl_up(Sw, 2);  if (lane >= 2)  Sw = fmaf(n2, u, Sw);
      u = __shfl_up(Sw, 4);  if (lane >= 4)  Sw = fmaf(n4, u, Sw);
      u = __shfl_up(Sw, 8);  if (lane >= 8)  Sw = fmaf(n8, u, Sw);
      u = __shfl_up(Sw, 16); if (lane >= 16) Sw = fmaf(n16, u, Sw);
      u = __shfl_up(Sw, 32); if (lane >= 32) Sw = fmaf(n32, u, Sw);
      float Sex = __shfl_up(Sw, 1);
      if (lane == 0) Sex = 0.0f;
      float v = fmaf(c32lane, tpre, Sex);
      const int o = (ls << 11) + (lane << 5);
#pragma unroll
      for (int i = 0; i < 8; ++i) {
        float4 y;
        v = fmaf(c, v, scale * pf[i].x); y.x = v;
        v = fmaf(c, v, scale * pf[i].y); y.y = v;
        v = fmaf(c, v, scale * pf[i].z); y.z = v;
        v = fmaf(c, v, scale * pf[i].w); y.w = v;
        *(float4*)&xall[o + 4 * i] = y;
      }
      if (lane == 0) {
        // release: drains the ds_writes above before publishing
        __hip_atomic_store(&prog[ls], 1, __ATOMIC_RELEASE,
                           __HIP_MEMORY_SCOPE_WORKGROUP);
      }
    }
    // tables after production (well before the block-wide barrier)
    if (wid <= 2) gen_tables(tabs, (wid - 1) * 64 + lane);
  }
}

// One-pole scan over [s2, s2+nt*2048) from global into LDS sl[n-s2], reads
// clamped at `lim`.
__device__ inline void lpc_lds(const float* __restrict__ xg,
                               float* __restrict__ sl, int s2, int nt, int lim,
                               float scale, float c, int t, float* lws) {
  const int lane = t & 63, wid = t >> 6;
  float c2v = c * c, c4 = c2v * c2v, c8 = c4 * c4;
  float m1 = c8, m2 = m1 * m1, m4 = m2 * m2, m8 = m4 * m4, m16 = m8 * m8,
        m32 = m16 * m16;
  float c512 = m32 * m32;
  float c2048 = c512 * c512;
  c2048 *= c2048;
  float l2c = log2f(c);
  float c8lane = exp2f((float)(8 * lane) * l2c);
  float cgk = exp2f((float)(8 * t) * l2c);
  float vrun = 0.0f;
  for (int tile = 0; tile < nt; ++tile) {
    __syncthreads();
    int g0 = s2 + (tile << 11) + 8 * t;
    float4 xa = make_float4(0.f, 0.f, 0.f, 0.f);
    float4 xb = make_float4(0.f, 0.f, 0.f, 0.f);
    if (g0 + 3 < lim) xa = *(const float4*)&xg[g0];
    if (g0 + 7 < lim) xb = *(const float4*)&xg[g0 + 4];
    float S = 0.0f;
    S = fmaf(c, S, scale * xa.x); S = fmaf(c, S, scale * xa.y);
    S = fmaf(c, S, scale * xa.z); S = fmaf(c, S, scale * xa.w);
    S = fmaf(c, S, scale * xb.x); S = fmaf(c, S, scale * xb.y);
    S = fmaf(c, S, scale * xb.z); S = fmaf(c, S, scale * xb.w);
    float Sw = S, u;
    u = __shfl_up(Sw, 1);  if (lane >= 1)  Sw = fmaf(m1, u, Sw);
    u = __shfl_up(Sw, 2);  if (lane >= 2)  Sw = fmaf(m2, u, Sw);
    u = __shfl_up(Sw, 4);  if (lane >= 4)  Sw = fmaf(m4, u, Sw);
    u = __shfl_up(Sw, 8);  if (lane >= 8)  Sw = fmaf(m8, u, Sw);
    u = __shfl_up(Sw, 16); if (lane >= 16) Sw = fmaf(m16, u, Sw);
    u = __shfl_up(Sw, 32); if (lane >= 32) Sw = fmaf(m32, u, Sw);
    if (lane == 63) lws[wid] = Sw;
    __syncthreads();
    float a0 = lws[0], a1w = lws[1], a2w = lws[2], a3w = lws[3];
    float carry = (wid == 1)   ? a0
                  : (wid == 2) ? fmaf(c512, a0, a1w)
                  : (wid == 3) ? fmaf(c512, fmaf(c512, a0, a1w), a2w)
                               : 0.0f;
    float Sprev = __shfl_up(Sw, 1);
    float Sex = (lane == 0) ? 0.0f : Sprev;
    Sex = fmaf(c8lane, carry, Sex);
    float v = fmaf(cgk, vrun, Sex);
    int o = g0 - s2;
    float4 ya, yb;
    v = fmaf(c, v, scale * xa.x); ya.x = v;
    v = fmaf(c, v, scale * xa.y); ya.y = v;
    v = fmaf(c, v, scale * xa.z); ya.z = v;
    v = fmaf(c, v, scale * xa.w); ya.w = v;
    v = fmaf(c, v, scale * xb.x); yb.x = v;
    v = fmaf(c, v, scale * xb.y); yb.y = v;
    v = fmaf(c, v, scale * xb.z); yb.z = v;
    v = fmaf(c, v, scale * xb.w); yb.w = v;
    *(float4*)&sl[o] = ya;
    *(float4*)&sl[o + 4] = yb;
    float tS = fmaf(c512, fmaf(c512, fmaf(c512, a0, a1w), a2w), a3w);
    vrun = fmaf(c2048, vrun, tS);
  }
}

// ---- body phase, T2=1024; matrix powers loaded from LDS tables ----
__device__ inline void body_phase(int b, int q, const BParams& P,
                                  const float* __restrict__ gains,
                                  const float* __restrict__ buf1,
                                  float* __restrict__ out, float* sl,
                                  float* lws, float (*lc0)[8],
                                  float (*lc1)[8], const float* tabs, int t) {
  const int lane = t & 63, wid = t >> 6;
  const int n0 = q << 10;
  const int base = n0 - 4096;
  int s2 = base - 256;
  if (s2 < 0) s2 = 0;
  const int end = n0 + 1024;
  const int nt = (end - s2 + 2047) >> 11;  // <= 3

  lpc_lds(buf1 + (size_t)b * NSAMP, sl, s2, nt, end, P.alpha_p,
          1.0f - P.alpha_p, t, lws);
  __syncthreads();

  const float* bandcL = tabs;
  const float* QlevL = tabs + 96;
  const float* QwL = tabs + 672;
  const float* RtabL = tabs + 768;

  const int tb = base + 20 * t;
  float4 acc[5];
#pragma unroll
  for (int i = 0; i < 5; ++i) acc[i] = make_float4(0.f, 0.f, 0.f, 0.f);

  for (int g = 0; g < 3; ++g) {
    float A1[8], A2[8], B0[8], GN[8];
#pragma unroll
    for (int j = 0; j < 8; ++j) {
      int k = g * 8 + j;
      float4 bc = *(const float4*)&bandcL[k * 4];
      A1[j] = bc.x; A2[j] = bc.y; B0[j] = bc.z;
      GN[j] = gains[k];
    }
    float cv0[8], cv1[8];
#pragma unroll
    for (int j = 0; j < 8; ++j) cv0[j] = cv1[j] = 0.f;
    for (int i = 0; i < 5; ++i) {
      int n = tb + 4 * i;
      float4 xv = make_float4(0.f, 0.f, 0.f, 0.f);
      if (n >= 0) xv = *(const float4*)&sl[n - s2];
#pragma unroll
      for (int e = 0; e < 4; ++e) {
        float xi = e == 0 ? xv.x : e == 1 ? xv.y : e == 2 ? xv.z : xv.w;
#pragma unroll
        for (int j = 0; j < 8; ++j) {
          float nc = fmaf(B0[j], xi, -fmaf(A1[j], cv0[j], A2[j] * cv1[j]));
          cv1[j] = cv0[j];
          cv0[j] = nc;
        }
      }
    }
    int kl = 0;
    for (int off = 1; off <= 32; off <<= 1, ++kl) {
      float q00[8], q01[8], q10[8], q11[8];
#pragma unroll
      for (int j = 0; j < 8; ++j) {
        float4 qv = *(const float4*)&QlevL[(kl * 24 + g * 8 + j) * 4];
        q00[j] = qv.x; q01[j] = qv.y; q10[j] = qv.z; q11[j] = qv.w;
      }
#pragma unroll
      for (int j = 0; j < 8; ++j) {
        float u0 = __shfl_up(cv0[j], off);
        float u1 = __shfl_up(cv1[j], off);
        if (lane >= off) {
          float nc0 = fmaf(q00[j], u0, fmaf(q01[j], u1, cv0[j]));
          float nc1 = fmaf(q10[j], u0, fmaf(q11[j], u1, cv1[j]));
          cv0[j] = nc0;
          cv1[j] = nc1;
        }
      }
    }
    __syncthreads();
    if (lane == 63) {
#pragma unroll
      for (int j = 0; j < 8; ++j) {
        lc0[wid][j] = cv0[j];
        lc1[wid][j] = cv1[j];
      }
    }
    __syncthreads();
    float qw00[8], qw01[8], qw10[8], qw11[8];
#pragma unroll
    for (int j = 0; j < 8; ++j) {
      float4 qv = *(const float4*)&QwL[(g * 8 + j) * 4];
      qw00[j] = qv.x; qw01[j] = qv.y; qw10[j] = qv.z; qw11[j] = qv.w;
    }
    float car0[8], car1[8];
#pragma unroll
    for (int j = 0; j < 8; ++j) car0[j] = car1[j] = 0.f;
    for (int v = 0; v < wid; ++v) {
#pragma unroll
      for (int j = 0; j < 8; ++j) {
        float n0c = fmaf(qw00[j], car0[j], fmaf(qw01[j], car1[j], lc0[v][j]));
        float n1c = fmaf(qw10[j], car0[j], fmaf(qw11[j], car1[j], lc1[v][j]));
        car0[j] = n0c;
        car1[j] = n1c;
      }
    }
    float y1[8], y2[8];
#pragma unroll
    for (int j = 0; j < 8; ++j) {
      float4 rv = *(const float4*)&RtabL[((g * 8 + j) * 64 + lane) * 4];
      float e0 = __shfl_up(cv0[j], 1);
      float e1 = __shfl_up(cv1[j], 1);
      if (lane == 0) { e0 = 0.f; e1 = 0.f; }
      y1[j] = fmaf(rv.x, car0[j], fmaf(rv.y, car1[j], e0));
      y2[j] = fmaf(rv.z, car0[j], fmaf(rv.w, car1[j], e1));
    }
    if (tb + 20 > n0) {
      for (int i = 0; i < 5; ++i) {
        float4 xv = *(const float4*)&sl[tb - s2 + 4 * i];
        float4 ov = acc[i];
#pragma unroll
        for (int e = 0; e < 4; ++e) {
          float xi = e == 0 ? xv.x : e == 1 ? xv.y : e == 2 ? xv.z : xv.w;
          float a = 0.f;
#pragma unroll
          for (int j = 0; j < 8; ++j) {
            float yv = fmaf(B0[j], xi, -fmaf(A1[j], y1[j], A2[j] * y2[j]));
            y2[j] = y1[j];
            y1[j] = yv;
            a = fmaf(GN[j], yv, a);
          }
          if (e == 0) ov.x += a;
          else if (e == 1) ov.y += a;
          else if (e == 2) ov.z += a;
          else ov.w += a;
        }
        acc[i] = ov;
      }
    }
  }
  if (tb + 20 > n0) {
    float* outb = out + (size_t)b * NSAMP;
#pragma unroll
    for (int i = 0; i < 5; ++i) {
      int n = tb + 4 * i;
      if (n >= n0) *(float4*)&outb[n] = acc[i];
    }
  }
}

// ======== single kernel, 256 blocks; dynamic LDS 162880 B ========
__global__ void __launch_bounds__(256, 1) synth_all(
    const float* __restrict__ exc, const float* __restrict__ pitch,
    const float* __restrict__ w1, const float* __restrict__ b1,
    const float* __restrict__ w2, const float* __restrict__ b2,
    const float* __restrict__ eg, const float* __restrict__ gains,
    float* __restrict__ buf1, int* __restrict__ flags,
    float* __restrict__ out) {
  extern __shared__ float smem[];
  const int blk = blockIdx.x;
  const int b = blk >> 5, q = blk & 31;
  const int t = threadIdx.x;

  BParams P = compute_params(b, pitch, w1, b1, w2, b2);
  if (blk == 0 && t < 64) {
    int bb = (t < 8) ? t : 0;
    BParams Q = compute_params(bb, pitch, w1, b1, w2, b2);
    float slc = 0.f, slm = 0.f, slp = 0.f;
    for (int i = 0; i < 8; ++i) {
      slc += rlv(Q.lc, i);
      slm += rlv(Q.lm, i);
      slp += rlv(Q.lp, i);
    }
    if (t == 0) {
      out[8 * NSAMP + 0] = slc / 8.0f;
      out[8 * NSAMP + 1] = slm / 8.0f;
      out[8 * NSAMP + 2] = slp / 8.0f;
    }
  }

  // ---- phase 1: KS slice q (writes buf1[n0, n0+1024)); tables generated ----
  ks_phase(b, q, P, exc, eg[0], buf1, smem, (int*)&smem[PROG_OFF],
           smem + TABS_OFF, t);
  __syncthreads();  // drain wave0's global stores + table writes

  // ---- handoff: publish own flag, wait for same-batch predecessors ----
  const int n0 = q << 10;
  int s2 = n0 - 4096 - 256;
  if (s2 < 0) s2 = 0;
  const int qlo = s2 >> 10;
  if (t == 0) {
    __hip_atomic_store(&flags[blk], FLAG_MAGIC, __ATOMIC_RELEASE,
                       __HIP_MEMORY_SCOPE_AGENT);
    for (int f = qlo; f < q; ++f) {
      while (__hip_atomic_load(&flags[b * 32 + f], __ATOMIC_ACQUIRE,
                               __HIP_MEMORY_SCOPE_AGENT) != FLAG_MAGIC) {
        __builtin_amdgcn_s_sleep(8);
      }
    }
  }
  __syncthreads();

  // ---- phase 2: body slice q (xall region reused; tables persist) ----
  body_phase(b, q, P, gains, buf1, out, smem, smem + 6144,
             (float(*)[8])(smem + 6152), (float(*)[8])(smem + 6184),
             smem + TABS_OFF, t);
}

extern "C" void kernel_launch(void* const* d_in, const int* in_sizes, int n_in,
                              void* d_out, int out_size, void* d_ws, size_t ws_size,
                              hipStream_t stream) {
  const float* exc = (const float*)d_in[0];
  const float* pitch = (const float*)d_in[1];
  const float* w1 = (const float*)d_in[2];
  const float* b1 = (const float*)d_in[3];
  const float* w2 = (const float*)d_in[4];
  const float* b2 = (const float*)d_in[5];
  const float* eg = (const float*)d_in[6];
  const float* bg = (const float*)d_in[7];
  float* out = (float*)d_out;
  float* buf1 = (float*)d_ws;             // 8*NSAMP floats (KS output)
  int* flags = (int*)(buf1 + 8 * NSAMP);  // 256 flags (poison != MAGIC)

  static int lds_set = 0;
  if (!lds_set) {
    (void)hipFuncSetAttribute(reinterpret_cast<const void*>(synth_all),
                              hipFuncAttributeMaxDynamicSharedMemorySize,
                              SMEM_FLOATS * 4);
    lds_set = 1;
  }
  hipLaunchKernelGGL(synth_all, dim3(256), dim3(256), SMEM_FLOATS * 4, stream,
                     exc, pitch, w1, b1, w2, b2, eg, bg, buf1, flags, out);
}

// Round 11
// 109.618 us; speedup vs baseline: 1.0162x; 1.0162x over previous
//
#include <hip/hip_runtime.h>
#include <math.h>

#define NSAMP 32768
#define FS_F 44100.0f
#define PI_F 3.14159265358979323846f
#define T1 1024  // KS slice length (32 slices/batch)
#define FLAG_MAGIC 0x5A5A5A5A

// LDS layout (floats, dynamic):
//   xall [0, 33792)      whole-span preLP'd excitation (32768 + 1024 pad)
//   prog [33792,33808)   per-segment ready flags (16 ints)
//   tabs [33808, 40720)  body tables (bandc/Qlev/Qw/Rtab)
// body overlays: sl = [0,5376), body lws/lc0/lc1 at [6144..6248)
#define XALL_FLOATS 33792
#define PROG_OFF 33792
#define TABS_OFF 33808
#define SMEM_FLOATS 40720  // 162880 bytes (<= 163840)

struct BParams {
  float alpha, alpha_p;
  float fr, g, s;
  int Di;
  float lc, lm, lp;
};

__device__ inline float sigmoidf_(float x) { return 1.0f / (1.0f + expf(-x)); }

__device__ inline BParams compute_params(int b, const float* __restrict__ pitch,
                                         const float* __restrict__ w1,
                                         const float* __restrict__ b1,
                                         const float* __restrict__ w2,
                                         const float* __restrict__ b2) {
  BParams P;
  float p = pitch[b];
  float h[16];
#pragma unroll
  for (int i = 0; i < 16; ++i) {
    float v = fmaf(p, w1[i], b1[i]);
    h[i] = v > 0.0f ? v : 0.0f;
  }
  float m[3];
#pragma unroll
  for (int j = 0; j < 3; ++j) {
    float acc = b2[j];
#pragma unroll
    for (int i = 0; i < 16; ++i) acc = fmaf(h[i], w2[j * 16 + i], acc);
    m[j] = acc;
  }
  P.lc = fminf(fmaxf(m[0], -2.0f), 2.5f);
  P.lm = fminf(fmaxf(m[1], -2.5f), 0.0f);
  P.lp = fminf(fmaxf(m[2], -4.0f), 4.0f);
  P.g = 0.999f * sigmoidf_(P.lc);
  P.s = sigmoidf_(P.lm);
  float f0 = fmaxf(p, 60.0f);
  float D = fminf(fmaxf(FS_F / f0, 2.0f), 735.0f);
  int Di = (int)floorf(D);
  P.fr = D - (float)Di;
  P.Di = Di;
  float mult = fminf(fmaxf(2.0f + 6.0f * (f0 - 60.0f) / 600.0f, 2.0f), 8.0f);
  float cutoff = fminf(2.0f * PI_F * f0 * mult / FS_F, PI_F * 0.9f);
  P.alpha = 1.0f - expf(-cutoff);
  float cpost = fminf(PI_F * sigmoidf_(P.lp), PI_F * 0.99f);
  P.alpha_p = 1.0f - expf(-cpost);
  return P;
}

// lane helpers (wave64)
__device__ inline float rlv(float v, int l) {
  return __int_as_float(__builtin_amdgcn_readlane(__float_as_int(v), l));
}
__device__ inline float shr1(float v, float bnd) {
  return __int_as_float(__builtin_amdgcn_update_dpp(
      __float_as_int(bnd), __float_as_int(v), 0x138 /*wave_shr:1*/, 0xf, 0xf,
      false));
}
// rotate right by 1: lane0 <- lane63
__device__ inline float ror1(float v) {
  return __int_as_float(__builtin_amdgcn_update_dpp(
      __float_as_int(v), __float_as_int(v), 0x13C /*wave_ror:1*/, 0xf, 0xf,
      false));
}

__device__ inline void band_coef(int k, float& a1, float& a2, float& b0) {
  float fc = 80.0f * exp2f((float)k * (6.64385618977472436f / 23.0f));
  float w = 2.0f * PI_F * fc / FS_F;
  float r = expf(-PI_F * fc / (10.0f * FS_F));
  a1 = -2.0f * r * cosf(w);
  a2 = r * r;
  b0 = 1.0f - r;
}

// ---- data-independent body tables (verified bit-exact vs in-body compute) --
__device__ inline void gen_tables(float* __restrict__ tabs, int W) {
  if (W >= 120) return;
  const int j = W / 5, sub = W % 5;
  float A1, A2, B0;
  band_coef(j, A1, A2, B0);
  if (sub == 0) *(float4*)&tabs[j * 4] = make_float4(A1, A2, B0, 0.f);
  float Q00 = -A1, Q01 = -A2, Q10 = 1.f, Q11 = 0.f;
#pragma unroll
  for (int sq = 0; sq < 2; ++sq) {
    float n00 = fmaf(Q00, Q00, Q01 * Q10);
    float n01 = fmaf(Q00, Q01, Q01 * Q11);
    float n10 = fmaf(Q10, Q00, Q11 * Q10);
    float n11 = fmaf(Q10, Q01, Q11 * Q11);
    Q00 = n00; Q01 = n01; Q10 = n10; Q11 = n11;
  }
  float K00 = Q00, K01 = Q01, K10 = Q10, K11 = Q11;
#pragma unroll
  for (int sq = 0; sq < 2; ++sq) {
    float n00 = fmaf(Q00, Q00, Q01 * Q10);
    float n01 = fmaf(Q00, Q01, Q01 * Q11);
    float n10 = fmaf(Q10, Q00, Q11 * Q10);
    float n11 = fmaf(Q10, Q01, Q11 * Q11);
    Q00 = n00; Q01 = n01; Q10 = n10; Q11 = n11;
  }
  float L00[7], L01[7], L10[7], L11[7];
  L00[0] = fmaf(Q00, K00, Q01 * K10);
  L01[0] = fmaf(Q00, K01, Q01 * K11);
  L10[0] = fmaf(Q10, K00, Q11 * K10);
  L11[0] = fmaf(Q10, K01, Q11 * K11);
#pragma unroll
  for (int k = 0; k < 6; ++k) {
    float s00 = fmaf(L00[k], L00[k], L01[k] * L10[k]);
    float s01 = fmaf(L00[k], L01[k], L01[k] * L11[k]);
    float s10 = fmaf(L10[k], L00[k], L11[k] * L10[k]);
    float s11 = fmaf(L10[k], L01[k], L11[k] * L11[k]);
    L00[k + 1] = s00; L01[k + 1] = s01; L10[k + 1] = s10; L11[k + 1] = s11;
  }
  if (sub == 0) {
#pragma unroll
    for (int k = 0; k < 6; ++k)
      *(float4*)&tabs[96 + (k * 24 + j) * 4] =
          make_float4(L00[k], L01[k], L10[k], L11[k]);
    *(float4*)&tabs[672 + j * 4] = make_float4(L00[6], L01[6], L10[6], L11[6]);
  }
  int l0 = sub * 13, l1 = l0 + 13;
  if (l1 > 64) l1 = 64;
  for (int l = l0; l < l1; ++l) {
    float R00 = 1.f, R01 = 0.f, R10 = 0.f, R11 = 1.f;
#pragma unroll
    for (int bit = 0; bit < 6; ++bit) {
      if ((l >> bit) & 1) {
        float n00 = fmaf(L00[bit], R00, L01[bit] * R10);
        float n01 = fmaf(L00[bit], R01, L01[bit] * R11);
        float n10 = fmaf(L10[bit], R00, L11[bit] * R10);
        float n11 = fmaf(L10[bit], R01, L11[bit] * R11);
        R00 = n00; R01 = n01; R10 = n10; R11 = n11;
      }
    }
    *(float4*)&tabs[768 + (j * 64 + l) * 4] = make_float4(R00, R01, R10, R11);
  }
}

// producer: register load of one segment (32 samples/lane), guarded
__device__ inline void w1_load(const float* __restrict__ xg, int s1, int seg,
                               int lane, float4* pf) {
  const int base = s1 + (seg << 11) + (lane << 5);
#pragma unroll
  for (int i = 0; i < 8; ++i) {
    const int g = base + 4 * i;
    float4 v = make_float4(0.f, 0.f, 0.f, 0.f);
    if (g >= 0 && g + 3 < NSAMP) v = *(const float4*)&xg[g];
    pf[i] = v;
  }
}

// One KS period step (legacy 2-buffer rotate form; used for remainders and
// the live/store region). FP op sequence identical to R2..R10.
#define KS_STEP(STORES)                                                       \
  do {                                                                        \
    float b2v[KNUM], b3v[KNUM];                                               \
    b2v[0] = shr1(yp[0], p1);                                                 \
    _Pragma("unroll") for (int k = 1; k < KNUM; ++k)                          \
        b2v[k] = shr1(yp[k], ror1(yp[k - 1]));                                \
    b3v[0] = shr1(b2v[0], p2);                                                \
    _Pragma("unroll") for (int k = 1; k < KNUM; ++k)                          \
        b3v[k] = shr1(b2v[k], ror1(b2v[k - 1]));                              \
    float p1n = rlv(yp[KNUM - 1], lq1);                                       \
    float p2n = rlv(b2v[KNUM - 1], lq1);                                      \
    _Pragma("unroll") for (int k = 0; k < KNUM; ++k)                          \
        yp[k] =                                                               \
            fmaf(c0w, yp[k], fmaf(c2w, b3v[k], fmaf(c1w, b2v[k], xC[k])));    \
    p1 = p1n;                                                                 \
    p2 = p2n;                                                                 \
    if (STORES) {                                                             \
      _Pragma("unroll") for (int k = 0; k < KNUM; ++k) {                      \
        int i = lane + (k << 6);                                              \
        int n = s1 + rel + i;                                                 \
        bool okl = (k < KNUM - 1) || (lane <= lq1);                           \
        if (okl && n >= n0 && n < end) yg[n] = yp[k];                         \
      }                                                                       \
    }                                                                         \
    int r2 = rel + 2 * C;                                                     \
    if (r2 < span) {                                                          \
      const float* xp = &xall[r2 + lane];                                     \
      _Pragma("unroll") for (int k = 0; k < KNUM; ++k) {                      \
        xC[k] = xN[k];                                                        \
        xN[k] = xp[k << 6];                                                   \
      }                                                                       \
    } else {                                                                  \
      _Pragma("unroll") for (int k = 0; k < KNUM; ++k) xC[k] = xN[k];         \
    }                                                                         \
    rel += C;                                                                 \
  } while (0)

// Lean step on a named buffer: consumes XB (holds x at rel) and reloads XB
// with x at rel+2C (used two iterations later). No register rotation.
// Same fp sequence as KS_STEP(false) -> bit-identical.
#define KS_STEP_BUF(XB)                                                       \
  do {                                                                        \
    float b2v[KNUM], b3v[KNUM];                                               \
    b2v[0] = shr1(yp[0], p1);                                                 \
    _Pragma("unroll") for (int k = 1; k < KNUM; ++k)                          \
        b2v[k] = shr1(yp[k], ror1(yp[k - 1]));                                \
    b3v[0] = shr1(b2v[0], p2);                                                \
    _Pragma("unroll") for (int k = 1; k < KNUM; ++k)                          \
        b3v[k] = shr1(b2v[k], ror1(b2v[k - 1]));                              \
    float p1n = rlv(yp[KNUM - 1], lq1);                                       \
    float p2n = rlv(b2v[KNUM - 1], lq1);                                      \
    _Pragma("unroll") for (int k = 0; k < KNUM; ++k)                          \
        yp[k] =                                                               \
            fmaf(c0w, yp[k], fmaf(c2w, b3v[k], fmaf(c1w, b2v[k], XB[k])));    \
    p1 = p1n;                                                                 \
    p2 = p2n;                                                                 \
    int r2 = rel + 2 * C;                                                     \
    if (r2 < span) {                                                          \
      const float* xp = &xall[r2 + lane];                                     \
      _Pragma("unroll") for (int k = 0; k < KNUM; ++k) XB[k] = xp[k << 6];    \
    }                                                                         \
    rel += C;                                                                 \
  } while (0)

// ---- single-wave KS recurrence (wave 0): flat LDS input; polls per-segment
// ready flags. Lean region runs pair-unrolled (no xC<-xN rotation).
template <int KNUM>
__device__ void ks_wave0(float* __restrict__ yg, const float* xall,
                         int* __restrict__ prog, int lane, int C, float c0w,
                         float c1w, float c2w, int s1, int n0, int end,
                         int span, int NSG) {
  const int lq1 = (C - 1) - (KNUM - 1) * 64;
  const int W = n0 - s1;
  float yp[KNUM], xC[KNUM], xN[KNUM];
  float p1 = 0.f, p2 = 0.f;
  int rel = 0;
  int done = 0;
#pragma unroll
  for (int k = 0; k < KNUM; ++k) { yp[k] = 0.f; xC[k] = 0.f; xN[k] = 0.f; }
  for (int s = 0; s < NSG; ++s) {
    int need = s + 3;
    if (need > NSG) need = NSG;
    for (; done < need; ++done) {
      while (__hip_atomic_load(&prog[done], __ATOMIC_ACQUIRE,
                               __HIP_MEMORY_SCOPE_WORKGROUP) == 0) {
        __builtin_amdgcn_s_sleep(1);
      }
    }
    if (s == 0) {
#pragma unroll
      for (int k = 0; k < KNUM; ++k) {
        int i = lane + (k << 6);
        xC[k] = xall[i];
        xN[k] = xall[C + i];
      }
    }
    int fence = (s + 1) << 11;
    if (fence > span) fence = span;
    // lean pairs: stepA consumes xC (rel), reloads xC with rel+2C;
    // stepB consumes xN (rel+C), reloads xN with rel+3C. Invariant
    // (xC=cur, xN=next) holds at loop exit -> compatible with KS_STEP.
    while (rel + 2 * C <= W && rel + C < fence) {
      KS_STEP_BUF(xC);
      KS_STEP_BUF(xN);
    }
    while (rel + C <= W && rel < fence) KS_STEP(false);
    while (rel < fence) KS_STEP(true);
  }
}

// ---- KS phase: waves 1-3 produce segments ls = (wid-1), (wid-1)+3, ...
// Each producer derives its carry from the PREVIOUS segment's total computed
// from scratch (exact: c^2048 <= e^-35 makes the recursive carry term
// sub-ulp, so vrun(s) == tot(s-1) in fp32). Per-segment LDS ready flags;
// consumer (wave0, setprio(1)) polls. Tables by waves 1-2 after production.
__device__ inline void ks_phase(int b, int q, const BParams& P,
                                const float* __restrict__ exc, float scale0,
                                float* __restrict__ buf1, float* xall,
                                int* prog, float* tabs, int t) {
  const int C = P.Di;
  const int n0 = q << 10;
  float lg = -logf(P.g);
  int Wp = (int)ceilf(10.5f / fmaxf(lg, 1e-6f));
  if (Wp > 64) Wp = 64;
  if (Wp < 4) Wp = 4;
  int W = Wp * C;
  if (W > n0) W = n0;
  W = (W + 3) & ~3;
  const int s1 = n0 - W;
  const int span = W + T1;
  const int end = n0 + T1;
  const int NSG = (span + 2047) >> 11;  // segments covering span, <= 16
  float* yg = buf1 + (size_t)b * NSAMP;
  const float* xg = exc + (size_t)b * NSAMP;

  const float c = 1.0f - P.alpha;
  const float scale = scale0 * P.alpha;
  const int lane = t & 63, wid = t >> 6;

  // init: per-segment flags + zero the pad region [NSG*2048, +1024)
  if (t < 16) prog[t] = 0;
  *(float4*)&xall[(NSG << 11) + 4 * t] = make_float4(0.f, 0.f, 0.f, 0.f);
  __syncthreads();

  const float c0w = P.g * (1.0f - P.s) * (1.0f - P.fr);
  const float c1w = P.g * ((1.0f - P.s) * P.fr + P.s * (1.0f - P.fr));
  const float c2w = P.g * P.s * P.fr;

  if (wid == 0) {
    __builtin_amdgcn_s_setprio(1);
    switch ((C + 63) >> 6) {
      case 2:  ks_wave0<2>(yg, xall, prog, lane, C, c0w, c1w, c2w, s1, n0, end, span, NSG); break;
      case 3:  ks_wave0<3>(yg, xall, prog, lane, C, c0w, c1w, c2w, s1, n0, end, span, NSG); break;
      case 4:  ks_wave0<4>(yg, xall, prog, lane, C, c0w, c1w, c2w, s1, n0, end, span, NSG); break;
      case 5:  ks_wave0<5>(yg, xall, prog, lane, C, c0w, c1w, c2w, s1, n0, end, span, NSG); break;
      case 6:  ks_wave0<6>(yg, xall, prog, lane, C, c0w, c1w, c2w, s1, n0, end, span, NSG); break;
      case 7:  ks_wave0<7>(yg, xall, prog, lane, C, c0w, c1w, c2w, s1, n0, end, span, NSG); break;
      case 8:  ks_wave0<8>(yg, xall, prog, lane, C, c0w, c1w, c2w, s1, n0, end, span, NSG); break;
      case 9:  ks_wave0<9>(yg, xall, prog, lane, C, c0w, c1w, c2w, s1, n0, end, span, NSG); break;
      case 10: ks_wave0<10>(yg, xall, prog, lane, C, c0w, c1w, c2w, s1, n0, end, span, NSG); break;
      case 11: ks_wave0<11>(yg, xall, prog, lane, C, c0w, c1w, c2w, s1, n0, end, span, NSG); break;
      default: ks_wave0<12>(yg, xall, prog, lane, C, c0w, c1w, c2w, s1, n0, end, span, NSG); break;
    }
    __builtin_amdgcn_s_setprio(0);
  } else {
    // ---- producers (waves 1..3) ----
    float c2v = c * c, c4 = c2v * c2v, c8 = c4 * c4;
    float m1 = c8, m2 = m1 * m1, m4 = m2 * m2, m8 = m4 * m4, m16 = m8 * m8,
          m32 = m16 * m16;
    float c512 = m32 * m32;
    const float n1 = m4, n2 = m8, n4 = m16, n8 = m32, n16 = c512,
                n32 = c512 * c512;
    const float c32lane = exp2f((float)(lane << 5) * log2f(c));
    for (int ls = wid - 1; ls < NSG; ls += 3) {
      // issue both segments' loads up front (latency overlap)
      float4 pp[8], pf[8];
      w1_load(xg, s1, ls - 1, lane, pp);  // previous segment (for carry)
      w1_load(xg, s1, ls, lane, pf);      // own segment
      // total of previous segment (same expression order as old vrun path)
      float Sp = 0.0f;
#pragma unroll
      for (int i = 0; i < 8; ++i) {
        Sp = fmaf(c, Sp, scale * pp[i].x);
        Sp = fmaf(c, Sp, scale * pp[i].y);
        Sp = fmaf(c, Sp, scale * pp[i].z);
        Sp = fmaf(c, Sp, scale * pp[i].w);
      }
      float Swp = Sp, up;
      up = __shfl_up(Swp, 1);  if (lane >= 1)  Swp = fmaf(n1, up, Swp);
      up = __shfl_up(Swp, 2);  if (lane >= 2)  Swp = fmaf(n2, up, Swp);
      up = __shfl_up(Swp, 4);  if (lane >= 4)  Swp = fmaf(n4, up, Swp);
      up = __shfl_up(Swp, 8);  if (lane >= 8)  Swp = fmaf(n8, up, Swp);
      up = __shfl_up(Swp, 16); if (lane >= 16) Swp = fmaf(n16, up, Swp);
      up = __shfl_up(Swp, 32); if (lane >= 32) Swp = fmaf(n32, up, Swp);
      float tpre = rlv(Swp, 63);  // == vrun entering segment ls (sub-ulp)
      // own segment scan
      float S = 0.0f;
#pragma unroll
      for (int i = 0; i < 8; ++i) {
        S = fmaf(c, S, scale * pf[i].x);
        S = fmaf(c, S, scale * pf[i].y);
        S = fmaf(c, S, scale * pf[i].z);
        S = fmaf(c, S, scale * pf[i].w);
      }
      float Sw = S, u;
      u = __shfl_up(Sw, 1);  if (lane >= 1)  Sw = fmaf(n1, u, Sw);
      u = __shfl_up(Sw, 2);  if (lane >= 2)  Sw = fmaf(n2, u, Sw);
      u = __shfl_up(Sw, 4);  if (lane >= 4)  Sw = fmaf(n4, u, Sw);
      u = __shfl_up(Sw, 8);  if (lane >= 8)  Sw = fmaf(n8, u, Sw);
      u = __shfl_up(Sw, 16); if (lane >= 16) Sw = fmaf(n16, u, Sw);
      u = __shfl_up(Sw, 32); if (lane >= 32) Sw = fmaf(n32, u, Sw);
      float Sex = __shfl_up(Sw, 1);
      if (lane == 0) Sex = 0.0f;
      float v = fmaf(c32lane, tpre, Sex);
      const int o = (ls << 11) + (lane << 5);
#pragma unroll
      for (int i = 0; i < 8; ++i) {
        float4 y;
        v = fmaf(c, v, scale * pf[i].x); y.x = v;
        v = fmaf(c, v, scale * pf[i].y); y.y = v;
        v = fmaf(c, v, scale * pf[i].z); y.z = v;
        v = fmaf(c, v, scale * pf[i].w); y.w = v;
        *(float4*)&xall[o + 4 * i] = y;
      }
      if (lane == 0) {
        // release: drains the ds_writes above before publishing
        __hip_atomic_store(&prog[ls], 1, __ATOMIC_RELEASE,
                           __HIP_MEMORY_SCOPE_WORKGROUP);
      }
    }
    // tables after production (well before the block-wide barrier)
    if (wid <= 2) gen_tables(tabs, (wid - 1) * 64 + lane);
  }
}

// One-pole scan over [s2, s2+nt*2048) from global into LDS sl[n-s2], reads
// clamped at `lim`.
__device__ inline void lpc_lds(const float* __restrict__ xg,
                               float* __restrict__ sl, int s2, int nt, int lim,
                               float scale, float c, int t, float* lws) {
  const int lane = t & 63, wid = t >> 6;
  float c2v = c * c, c4 = c2v * c2v, c8 = c4 * c4;
  float m1 = c8, m2 = m1 * m1, m4 = m2 * m2, m8 = m4 * m4, m16 = m8 * m8,
        m32 = m16 * m16;
  float c512 = m32 * m32;
  float c2048 = c512 * c512;
  c2048 *= c2048;
  float l2c = log2f(c);
  float c8lane = exp2f((float)(8 * lane) * l2c);
  float cgk = exp2f((float)(8 * t) * l2c);
  float vrun = 0.0f;
  for (int tile = 0; tile < nt; ++tile) {
    __syncthreads();
    int g0 = s2 + (tile << 11) + 8 * t;
    float4 xa = make_float4(0.f, 0.f, 0.f, 0.f);
    float4 xb = make_float4(0.f, 0.f, 0.f, 0.f);
    if (g0 + 3 < lim) xa = *(const float4*)&xg[g0];
    if (g0 + 7 < lim) xb = *(const float4*)&xg[g0 + 4];
    float S = 0.0f;
    S = fmaf(c, S, scale * xa.x); S = fmaf(c, S, scale * xa.y);
    S = fmaf(c, S, scale * xa.z); S = fmaf(c, S, scale * xa.w);
    S = fmaf(c, S, scale * xb.x); S = fmaf(c, S, scale * xb.y);
    S = fmaf(c, S, scale * xb.z); S = fmaf(c, S, scale * xb.w);
    float Sw = S, u;
    u = __shfl_up(Sw, 1);  if (lane >= 1)  Sw = fmaf(m1, u, Sw);
    u = __shfl_up(Sw, 2);  if (lane >= 2)  Sw = fmaf(m2, u, Sw);
    u = __shfl_up(Sw, 4);  if (lane >= 4)  Sw = fmaf(m4, u, Sw);
    u = __shfl_up(Sw, 8);  if (lane >= 8)  Sw = fmaf(m8, u, Sw);
    u = __shfl_up(Sw, 16); if (lane >= 16) Sw = fmaf(m16, u, Sw);
    u = __shfl_up(Sw, 32); if (lane >= 32) Sw = fmaf(m32, u, Sw);
    if (lane == 63) lws[wid] = Sw;
    __syncthreads();
    float a0 = lws[0], a1w = lws[1], a2w = lws[2], a3w = lws[3];
    float carry = (wid == 1)   ? a0
                  : (wid == 2) ? fmaf(c512, a0, a1w)
                  : (wid == 3) ? fmaf(c512, fmaf(c512, a0, a1w), a2w)
                               : 0.0f;
    float Sprev = __shfl_up(Sw, 1);
    float Sex = (lane == 0) ? 0.0f : Sprev;
    Sex = fmaf(c8lane, carry, Sex);
    float v = fmaf(cgk, vrun, Sex);
    int o = g0 - s2;
    float4 ya, yb;
    v = fmaf(c, v, scale * xa.x); ya.x = v;
    v = fmaf(c, v, scale * xa.y); ya.y = v;
    v = fmaf(c, v, scale * xa.z); ya.z = v;
    v = fmaf(c, v, scale * xa.w); ya.w = v;
    v = fmaf(c, v, scale * xb.x); yb.x = v;
    v = fmaf(c, v, scale * xb.y); yb.y = v;
    v = fmaf(c, v, scale * xb.z); yb.z = v;
    v = fmaf(c, v, scale * xb.w); yb.w = v;
    *(float4*)&sl[o] = ya;
    *(float4*)&sl[o + 4] = yb;
    float tS = fmaf(c512, fmaf(c512, fmaf(c512, a0, a1w), a2w), a3w);
    vrun = fmaf(c2048, vrun, tS);
  }
}

// ---- body phase, T2=1024; matrix powers loaded from LDS tables ----
__device__ inline void body_phase(int b, int q, const BParams& P,
                                  const float* __restrict__ gains,
                                  const float* __restrict__ buf1,
                                  float* __restrict__ out, float* sl,
                                  float* lws, float (*lc0)[8],
                                  float (*lc1)[8], const float* tabs, int t) {
  const int lane = t & 63, wid = t >> 6;
  const int n0 = q << 10;
  const int base = n0 - 4096;
  int s2 = base - 256;
  if (s2 < 0) s2 = 0;
  const int end = n0 + 1024;
  const int nt = (end - s2 + 2047) >> 11;  // <= 3

  lpc_lds(buf1 + (size_t)b * NSAMP, sl, s2, nt, end, P.alpha_p,
          1.0f - P.alpha_p, t, lws);
  __syncthreads();

  const float* bandcL = tabs;
  const float* QlevL = tabs + 96;
  const float* QwL = tabs + 672;
  const float* RtabL = tabs + 768;

  const int tb = base + 20 * t;
  float4 acc[5];
#pragma unroll
  for (int i = 0; i < 5; ++i) acc[i] = make_float4(0.f, 0.f, 0.f, 0.f);

  for (int g = 0; g < 3; ++g) {
    float A1[8], A2[8], B0[8], GN[8];
#pragma unroll
    for (int j = 0; j < 8; ++j) {
      int k = g * 8 + j;
      float4 bc = *(const float4*)&bandcL[k * 4];
      A1[j] = bc.x; A2[j] = bc.y; B0[j] = bc.z;
      GN[j] = gains[k];
    }
    float cv0[8], cv1[8];
#pragma unroll
    for (int j = 0; j < 8; ++j) cv0[j] = cv1[j] = 0.f;
    for (int i = 0; i < 5; ++i) {
      int n = tb + 4 * i;
      float4 xv = make_float4(0.f, 0.f, 0.f, 0.f);
      if (n >= 0) xv = *(const float4*)&sl[n - s2];
#pragma unroll
      for (int e = 0; e < 4; ++e) {
        float xi = e == 0 ? xv.x : e == 1 ? xv.y : e == 2 ? xv.z : xv.w;
#pragma unroll
        for (int j = 0; j < 8; ++j) {
          float nc = fmaf(B0[j], xi, -fmaf(A1[j], cv0[j], A2[j] * cv1[j]));
          cv1[j] = cv0[j];
          cv0[j] = nc;
        }
      }
    }
    int kl = 0;
    for (int off = 1; off <= 32; off <<= 1, ++kl) {
      float q00[8], q01[8], q10[8], q11[8];
#pragma unroll
      for (int j = 0; j < 8; ++j) {
        float4 qv = *(const float4*)&QlevL[(kl * 24 + g * 8 + j) * 4];
        q00[j] = qv.x; q01[j] = qv.y; q10[j] = qv.z; q11[j] = qv.w;
      }
#pragma unroll
      for (int j = 0; j < 8; ++j) {
        float u0 = __shfl_up(cv0[j], off);
        float u1 = __shfl_up(cv1[j], off);
        if (lane >= off) {
          float nc0 = fmaf(q00[j], u0, fmaf(q01[j], u1, cv0[j]));
          float nc1 = fmaf(q10[j], u0, fmaf(q11[j], u1, cv1[j]));
          cv0[j] = nc0;
          cv1[j] = nc1;
        }
      }
    }
    __syncthreads();
    if (lane == 63) {
#pragma unroll
      for (int j = 0; j < 8; ++j) {
        lc0[wid][j] = cv0[j];
        lc1[wid][j] = cv1[j];
      }
    }
    __syncthreads();
    float qw00[8], qw01[8], qw10[8], qw11[8];
#pragma unroll
    for (int j = 0; j < 8; ++j) {
      float4 qv = *(const float4*)&QwL[(g * 8 + j) * 4];
      qw00[j] = qv.x; qw01[j] = qv.y; qw10[j] = qv.z; qw11[j] = qv.w;
    }
    float car0[8], car1[8];
#pragma unroll
    for (int j = 0; j < 8; ++j) car0[j] = car1[j] = 0.f;
    for (int v = 0; v < wid; ++v) {
#pragma unroll
      for (int j = 0; j < 8; ++j) {
        float n0c = fmaf(qw00[j], car0[j], fmaf(qw01[j], car1[j], lc0[v][j]));
        float n1c = fmaf(qw10[j], car0[j], fmaf(qw11[j], car1[j], lc1[v][j]));
        car0[j] = n0c;
        car1[j] = n1c;
      }
    }
    float y1[8], y2[8];
#pragma unroll
    for (int j = 0; j < 8; ++j) {
      float4 rv = *(const float4*)&RtabL[((g * 8 + j) * 64 + lane) * 4];
      float e0 = __shfl_up(cv0[j], 1);
      float e1 = __shfl_up(cv1[j], 1);
      if (lane == 0) { e0 = 0.f; e1 = 0.f; }
      y1[j] = fmaf(rv.x, car0[j], fmaf(rv.y, car1[j], e0));
      y2[j] = fmaf(rv.z, car0[j], fmaf(rv.w, car1[j], e1));
    }
    if (tb + 20 > n0) {
      for (int i = 0; i < 5; ++i) {
        float4 xv = *(const float4*)&sl[tb - s2 + 4 * i];
        float4 ov = acc[i];
#pragma unroll
        for (int e = 0; e < 4; ++e) {
          float xi = e == 0 ? xv.x : e == 1 ? xv.y : e == 2 ? xv.z : xv.w;
          float a = 0.f;
#pragma unroll
          for (int j = 0; j < 8; ++j) {
            float yv = fmaf(B0[j], xi, -fmaf(A1[j], y1[j], A2[j] * y2[j]));
            y2[j] = y1[j];
            y1[j] = yv;
            a = fmaf(GN[j], yv, a);
          }
          if (e == 0) ov.x += a;
          else if (e == 1) ov.y += a;
          else if (e == 2) ov.z += a;
          else ov.w += a;
        }
        acc[i] = ov;
      }
    }
  }
  if (tb + 20 > n0) {
    float* outb = out + (size_t)b * NSAMP;
#pragma unroll
    for (int i = 0; i < 5; ++i) {
      int n = tb + 4 * i;
      if (n >= n0) *(float4*)&outb[n] = acc[i];
    }
  }
}

// ======== single kernel, 256 blocks; dynamic LDS 162880 B ========
__global__ void __launch_bounds__(256, 1) synth_all(
    const float* __restrict__ exc, const float* __restrict__ pitch,
    const float* __restrict__ w1, const float* __restrict__ b1,
    const float* __restrict__ w2, const float* __restrict__ b2,
    const float* __restrict__ eg, const float* __restrict__ gains,
    float* __restrict__ buf1, int* __restrict__ flags,
    float* __restrict__ out) {
  extern __shared__ float smem[];
  const int blk = blockIdx.x;
  const int b = blk >> 5, q = blk & 31;
  const int t = threadIdx.x;

  BParams P = compute_params(b, pitch, w1, b1, w2, b2);
  if (blk == 0 && t < 64) {
    int bb = (t < 8) ? t : 0;
    BParams Q = compute_params(bb, pitch, w1, b1, w2, b2);
    float slc = 0.f, slm = 0.f, slp = 0.f;
    for (int i = 0; i < 8; ++i) {
      slc += rlv(Q.lc, i);
      slm += rlv(Q.lm, i);
      slp += rlv(Q.lp, i);
    }
    if (t == 0) {
      out[8 * NSAMP + 0] = slc / 8.0f;
      out[8 * NSAMP + 1] = slm / 8.0f;
      out[8 * NSAMP + 2] = slp / 8.0f;
    }
  }

  // ---- phase 1: KS slice q (writes buf1[n0, n0+1024)); tables generated ----
  ks_phase(b, q, P, exc, eg[0], buf1, smem, (int*)&smem[PROG_OFF],
           smem + TABS_OFF, t);
  __syncthreads();  // drain wave0's global stores + table writes

  // ---- handoff: publish own flag, wait for same-batch predecessors ----
  const int n0 = q << 10;
  int s2 = n0 - 4096 - 256;
  if (s2 < 0) s2 = 0;
  const int qlo = s2 >> 10;
  if (t == 0) {
    __hip_atomic_store(&flags[blk], FLAG_MAGIC, __ATOMIC_RELEASE,
                       __HIP_MEMORY_SCOPE_AGENT);
    for (int f = qlo; f < q; ++f) {
      while (__hip_atomic_load(&flags[b * 32 + f], __ATOMIC_ACQUIRE,
                               __HIP_MEMORY_SCOPE_AGENT) != FLAG_MAGIC) {
        __builtin_amdgcn_s_sleep(8);
      }
    }
  }
  __syncthreads();

  // ---- phase 2: body slice q (xall region reused; tables persist) ----
  body_phase(b, q, P, gains, buf1, out, smem, smem + 6144,
             (float(*)[8])(smem + 6152), (float(*)[8])(smem + 6184),
             smem + TABS_OFF, t);
}

extern "C" void kernel_launch(void* const* d_in, const int* in_sizes, int n_in,
                              void* d_out, int out_size, void* d_ws, size_t ws_size,
                              hipStream_t stream) {
  const float* exc = (const float*)d_in[0];
  const float* pitch = (const float*)d_in[1];
  const float* w1 = (const float*)d_in[2];
  const float* b1 = (const float*)d_in[3];
  const float* w2 = (const float*)d_in[4];
  const float* b2 = (const float*)d_in[5];
  const float* eg = (const float*)d_in[6];
  const float* bg = (const float*)d_in[7];
  float* out = (float*)d_out;
  float* buf1 = (float*)d_ws;             // 8*NSAMP floats (KS output)
  int* flags = (int*)(buf1 + 8 * NSAMP);  // 256 flags (poison != MAGIC)

  static int lds_set = 0;
  if (!lds_set) {
    (void)hipFuncSetAttribute(reinterpret_cast<const void*>(synth_all),
                              hipFuncAttributeMaxDynamicSharedMemorySize,
                              SMEM_FLOATS * 4);
    lds_set = 1;
  }
  hipLaunchKernelGGL(synth_all, dim3(256), dim3(256), SMEM_FLOATS * 4, stream,
                     exc, pitch, w1, b1, w2, b2, eg, bg, buf1, flags, out);
}